// Round 5
// baseline (450.245 us; speedup 1.0000x reference)
//
#include <hip/hip_runtime.h>
#include <hip/hip_bf16.h>
#include <math.h>

#define NPTS 30000
#define KNN  16
#define NB   30          // batches (of 4 points) per block
#define GRID 250         // 250 * 120 pts = 30000 exactly

typedef __attribute__((ext_vector_type(8)))  __bf16 bf16x8;
typedef __attribute__((ext_vector_type(16))) float  f32x16;
typedef __attribute__((ext_vector_type(4)))  float  f32x4;

__device__ __forceinline__ unsigned short f2bf(float x) {
    unsigned u = __builtin_bit_cast(unsigned, x);
    return (unsigned short)((u + 0x7FFFu + ((u >> 16) & 1u)) >> 16);   // RNE
}
__device__ __forceinline__ float bf_lo(unsigned u) { return __builtin_bit_cast(float, u << 16); }
__device__ __forceinline__ float bf_hi(unsigned u) { return __builtin_bit_cast(float, u & 0xffff0000u); }
__device__ __forceinline__ unsigned pk2(float a, float b) {
    return (unsigned)f2bf(a) | ((unsigned)f2bf(b) << 16);
}
// tanh-form GELU, 8 VALU ops: x*(1 - 1/(exp(1.5958*(x+0.044715x^3)) + 1))
__device__ __forceinline__ float gelu_t(float x) {
    float x2 = x * x;
    float u  = x * fmaf(0.07135481624f, x2, 1.59576912161f);
    float e  = __expf(u);
    float r  = __builtin_amdgcn_rcpf(e + 1.0f);
    return fmaf(-x, r, x);
}

// ---- prep: bf16 weight layouts in ws ----
// w1dt[d][k] = W1[128+k][d]          (256x128)  A-frags for GEMM1 (diff half)
// w2t [e][c] = W2[c][e]              (256x256)  B-frags for GEMM2
// wcst[col][k] = col<256 ? W1[k][col] : Ws[k][col-256]   (512x128) B for c2-pass
__global__ void prep_w(const float* __restrict__ W1, const float* __restrict__ W2,
                       const float* __restrict__ Ws,
                       unsigned short* __restrict__ w1dt, unsigned short* __restrict__ w2t,
                       unsigned short* __restrict__ wcst) {
    int t = blockIdx.x * 256 + threadIdx.x;          // grid 256*256 -> t < 65536
    {   int e = t >> 8, c = t & 255;
        w2t[t] = f2bf(W2[c * 256 + e]); }
    {   int col = t >> 7, k = t & 127;
        float v = (col < 256) ? W1[k * 256 + col] : Ws[k * 256 + (col - 256)];
        wcst[t] = f2bf(v); }
    if (t < 32768) {
        int d = t >> 7, k = t & 127;
        w1dt[t] = f2bf(W1[(128 + k) * 256 + d]); }
}

// 8 waves: wv 0-3 = GEMM1/stage waves (hold W1d^T), wv 4-7 = GEMM2/LN waves (hold W2^T).
// Pipeline per iter i: stage edge(i+1) | GEMM1(i)->h | GEMM2(i-1)->agg | LN(i-2)->out
// c2 tile (cterm+b1 | skip+bs+b2 for 16 pts) recomputed every 4 iters, double-buffered.
// NOTE: no min-waves arg — LDS (139KB) already pins 1 block/CU; constraining regs
// to 256/wave forced wfr[] spills to scratch (R4: WRITE_SIZE 264MB, FETCH 1GB).
__global__ __launch_bounds__(512) void edgeconv_main(
    const float* __restrict__ feat, const int* __restrict__ knn,
    const unsigned short* __restrict__ w1dt, const unsigned short* __restrict__ w2t,
    const unsigned short* __restrict__ wcst,
    const float* __restrict__ b1, const float* __restrict__ b2,
    const float* __restrict__ bs,
    const float* __restrict__ gamma, const float* __restrict__ beta,
    float* __restrict__ out)
{
    __shared__ __align__(16) unsigned char  s_edge[2][64 * 256];   // diff-edge, bf16, swizzled
    __shared__ __align__(16) unsigned char  s_h[2][64 * 512];      // h, bf16, swizzled
    __shared__ __align__(16) unsigned short s_c2[2][16][512];      // [pt][cterm 0:256 | skip 256:512]
    __shared__ __align__(16) float s_agg[2][4][256];               // per-point channel max

    const int lane = threadIdx.x & 63;
    const int wv   = threadIdx.x >> 6;
    const int l31  = lane & 31;
    const int lh   = lane >> 5;
    const int l15  = lane & 15;
    const int l4   = lane >> 4;
    const int pblock = blockIdx.x * 120;
    const bool isG1 = (wv < 4);

    // persistent weight fragments (per-path SSA: G1 uses [0..15], G2 uses [0..31])
    bf16x8 wfr[32];
    if (isG1) {
        #pragma unroll
        for (int mb = 0; mb < 2; ++mb)
            #pragma unroll
            for (int ks = 0; ks < 8; ++ks)
                wfr[mb * 8 + ks] = *(const bf16x8*)(w1dt + (wv * 64 + mb * 32 + l31) * 128 + ks * 16 + lh * 8);
    } else {
        #pragma unroll
        for (int nb = 0; nb < 2; ++nb)
            #pragma unroll
            for (int ks = 0; ks < 16; ++ks)
                wfr[nb * 16 + ks] = *(const bf16x8*)(w2t + ((wv - 4) * 64 + nb * 32 + l31) * 256 + ks * 16 + lh * 8);
    }

    // c2-pass: 16 pts x 512 cols via 16x16x32 MFMA; all 8 waves, 4 col-tiles each
    auto c2pass = [&](int s) {
        const int buf = s & 1;
        const int pb  = pblock + s * 16;
        bf16x8 af[4];
        #pragma unroll
        for (int ks = 0; ks < 4; ++ks) {
            int p = pb + l15; p = (p < NPTS) ? p : (NPTS - 1);
            const float* fp = feat + (long)p * 128 + ks * 32 + l4 * 8;
            float4 f0 = *(const float4*)fp;
            float4 f1 = *(const float4*)(fp + 4);
            uint4 u;
            u.x = pk2(f0.x, f0.y); u.y = pk2(f0.z, f0.w);
            u.z = pk2(f1.x, f1.y); u.w = pk2(f1.z, f1.w);
            af[ks] = __builtin_bit_cast(bf16x8, u);
        }
        #pragma unroll
        for (int j = 0; j < 4; ++j) {
            const int ct  = wv * 4 + j;
            const int col = ct * 16 + l15;
            float bias = (ct < 16) ? b1[col] : (bs[col - 256] + b2[col - 256]);
            f32x4 acc = {bias, bias, bias, bias};
            #pragma unroll
            for (int ks = 0; ks < 4; ++ks) {
                bf16x8 bf = *(const bf16x8*)(wcst + col * 128 + ks * 32 + l4 * 8);
                acc = __builtin_amdgcn_mfma_f32_16x16x32_bf16(af[ks], bf, acc, 0, 0, 0);
            }
            #pragma unroll
            for (int r = 0; r < 4; ++r)
                s_c2[buf][l4 * 4 + r][col] = f2bf(acc[r]);
        }
    };

    // ---- prologue: stage batch 0, c2 tile s=0 ----
    if (isG1) {
        int n = pblock + wv;
        float2 cc0 = *(const float2*)(feat + (long)n * 128 + lane * 2);
        #pragma unroll
        for (int kk = 0; kk < 16; ++kk) {
            int idx = knn[n * 16 + kk];
            float2 nb2 = *(const float2*)(feat + (long)idx * 128 + lane * 2);
            int row = wv * 16 + kk;
            unsigned v = pk2(nb2.x - cc0.x, nb2.y - cc0.y);
            *(unsigned*)(s_edge[0] + row * 256 + ((unsigned)(lane * 4) ^ (unsigned)((row & 7) << 4))) = v;
        }
    }
    c2pass(0);
    __syncthreads();

    const f32x16 z16 = (f32x16)0.0f;

    #pragma unroll 1
    for (int i = 0; i < NB + 2; ++i) {
        // ---- stage loads for batch i+1 (issued early, stored after GEMM1) ----
        float2 cc; float2 nbr[16];
        const bool doStage = isG1 && (i + 1 < NB);
        if (doStage) {
            int n = pblock + (i + 1) * 4 + wv;
            cc = *(const float2*)(feat + (long)n * 128 + lane * 2);
            int idx[16];
            #pragma unroll
            for (int kk = 0; kk < 16; ++kk) idx[kk] = knn[n * 16 + kk];
            #pragma unroll
            for (int kk = 0; kk < 16; ++kk)
                nbr[kk] = *(const float2*)(feat + (long)idx[kk] * 128 + lane * 2);
        }

        if (isG1) {
            if (i < NB) {
                // ---- GEMM1: h[row][ch] = gelu(edge_diff . W1d + cterm), R=2 ----
                f32x16 acc[2][2] = {{z16, z16}, {z16, z16}};   // [mb][rowb]
                #pragma unroll
                for (int rowb = 0; rowb < 2; ++rowb) {
                    const int row = rowb * 32 + l31;
                    const unsigned swz = (unsigned)((row & 7) << 4);
                    #pragma unroll
                    for (int ks = 0; ks < 8; ++ks) {
                        bf16x8 bf = *(const bf16x8*)(s_edge[i & 1] + row * 256 + ((unsigned)(ks * 32 + lh * 16) ^ swz));
                        acc[0][rowb] = __builtin_amdgcn_mfma_f32_32x32x16_bf16(wfr[ks],     bf, acc[0][rowb], 0, 0, 0);
                        acc[1][rowb] = __builtin_amdgcn_mfma_f32_32x32x16_bf16(wfr[8 + ks], bf, acc[1][rowb], 0, 0, 0);
                    }
                }
                const int sB = (i >> 2) & 1;
                #pragma unroll
                for (int mb = 0; mb < 2; ++mb)
                #pragma unroll
                for (int rowb = 0; rowb < 2; ++rowb) {
                    const int row  = rowb * 32 + l31;
                    const int pt16 = (i & 3) * 4 + (row >> 4);
                    const unsigned swz = (unsigned)((row & 7) << 4);
                    #pragma unroll
                    for (int g = 0; g < 4; ++g) {
                        const int ch0 = wv * 64 + mb * 32 + 8 * g + 4 * lh;
                        uint2 c2v = *(const uint2*)(&s_c2[sB][pt16][ch0]);
                        float v0 = gelu_t(acc[mb][rowb][4 * g + 0] + bf_lo(c2v.x));
                        float v1 = gelu_t(acc[mb][rowb][4 * g + 1] + bf_hi(c2v.x));
                        float v2 = gelu_t(acc[mb][rowb][4 * g + 2] + bf_lo(c2v.y));
                        float v3 = gelu_t(acc[mb][rowb][4 * g + 3] + bf_hi(c2v.y));
                        uint2 hv; hv.x = pk2(v0, v1); hv.y = pk2(v2, v3);
                        *(uint2*)(s_h[i & 1] + row * 512 + ((unsigned)(ch0 * 2) ^ swz)) = hv;
                    }
                }
            }
            if (doStage) {   // convert + LDS-write the prefetched edge rows
                const int bt = i + 1;
                #pragma unroll
                for (int kk = 0; kk < 16; ++kk) {
                    int row = wv * 16 + kk;
                    unsigned v = pk2(nbr[kk].x - cc.x, nbr[kk].y - cc.y);
                    *(unsigned*)(s_edge[bt & 1] + row * 256 + ((unsigned)(lane * 4) ^ (unsigned)((row & 7) << 4))) = v;
                }
            }
        } else {
            // ---- LayerNorm + store for batch i-2 ----
            if (i >= 2) {
                const int bt2 = i - 2;
                const int pt  = wv - 4;
                const int n   = pblock + bt2 * 4 + pt;
                const int sB  = (bt2 >> 2) & 1;
                const int pt16 = (bt2 & 3) * 4 + pt;
                float4 ag = *(const float4*)&s_agg[bt2 & 1][pt][lane * 4];
                uint2 sk  = *(const uint2*)(&s_c2[sB][pt16][256 + lane * 4]);
                float x0 = ag.x + bf_lo(sk.x), x1 = ag.y + bf_hi(sk.x);
                float x2 = ag.z + bf_lo(sk.y), x3 = ag.w + bf_hi(sk.y);
                float s  = x0 + x1 + x2 + x3;
                float ss = fmaf(x0, x0, fmaf(x1, x1, fmaf(x2, x2, x3 * x3)));
                #pragma unroll
                for (int off = 1; off < 64; off <<= 1) {
                    s  += __shfl_xor(s, off);
                    ss += __shfl_xor(ss, off);
                }
                float mu   = s * (1.0f / 256.0f);
                float var  = ss * (1.0f / 256.0f) - mu * mu;
                float rstd = rsqrtf(var + 1e-5f);
                float4 g4 = *(const float4*)&gamma[lane * 4];
                float4 b4 = *(const float4*)&beta[lane * 4];
                float4 o;
                o.x = (x0 - mu) * rstd * g4.x + b4.x;
                o.y = (x1 - mu) * rstd * g4.y + b4.y;
                o.z = (x2 - mu) * rstd * g4.z + b4.z;
                o.w = (x3 - mu) * rstd * g4.w + b4.w;
                *(float4*)&out[(long)n * 256 + lane * 4] = o;
            }
            // ---- GEMM2: eo[row][ch] = h . W2, in-lane max over 16 rows ----
            if (i >= 1 && i <= NB) {
                const int bt = i - 1;
                f32x16 acc[2][2] = {{z16, z16}, {z16, z16}};   // [mb(rows)][nb(ch)]
                #pragma unroll
                for (int mb = 0; mb < 2; ++mb) {
                    const int row = mb * 32 + l31;
                    const unsigned swz = (unsigned)((row & 7) << 4);
                    #pragma unroll
                    for (int ks = 0; ks < 16; ++ks) {
                        bf16x8 af = *(const bf16x8*)(s_h[bt & 1] + row * 512 + ((unsigned)(ks * 32 + lh * 16) ^ swz));
                        acc[mb][0] = __builtin_amdgcn_mfma_f32_32x32x16_bf16(af, wfr[ks],      acc[mb][0], 0, 0, 0);
                        acc[mb][1] = __builtin_amdgcn_mfma_f32_32x32x16_bf16(af, wfr[16 + ks], acc[mb][1], 0, 0, 0);
                    }
                }
                #pragma unroll
                for (int mb = 0; mb < 2; ++mb)
                #pragma unroll
                for (int nb2 = 0; nb2 < 2; ++nb2) {
                    float m0 = acc[mb][nb2][0];
                    float m1 = acc[mb][nb2][8];
                    #pragma unroll
                    for (int r = 1; r < 8; ++r) {
                        m0 = fmaxf(m0, acc[mb][nb2][r]);
                        m1 = fmaxf(m1, acc[mb][nb2][8 + r]);
                    }
                    m0 = fmaxf(m0, __shfl_xor(m0, 32));
                    m1 = fmaxf(m1, __shfl_xor(m1, 32));
                    if (lh == 0) {
                        const int chb = (wv - 4) * 64 + nb2 * 32 + l31;
                        s_agg[bt & 1][mb * 2 + 0][chb] = m0;
                        s_agg[bt & 1][mb * 2 + 1][chb] = m1;
                    }
                }
            }
        }
        // ---- c2 tile for next super-batch (every 4 iters) ----
        if ((i & 3) == 2 && ((i >> 2) + 1) < 8)
            c2pass((i >> 2) + 1);
        __syncthreads();
    }
}

extern "C" void kernel_launch(void* const* d_in, const int* in_sizes, int n_in,
                              void* d_out, int out_size, void* d_ws, size_t ws_size,
                              hipStream_t stream) {
    const float* feat  = (const float*)d_in[0];
    const int*   knn   = (const int*)  d_in[1];
    const float* W1    = (const float*)d_in[2];
    const float* b1    = (const float*)d_in[3];
    const float* W2    = (const float*)d_in[4];
    const float* b2    = (const float*)d_in[5];
    const float* Ws    = (const float*)d_in[6];
    const float* bs    = (const float*)d_in[7];
    const float* gamma = (const float*)d_in[8];
    const float* beta  = (const float*)d_in[9];
    float* out = (float*)d_out;

    unsigned short* w1dt = (unsigned short*)d_ws;          //  64 KB
    unsigned short* w2t  = w1dt + 32768;                   // 128 KB
    unsigned short* wcst = w2t + 65536;                    // 128 KB  (total 320 KB)

    hipLaunchKernelGGL(prep_w, dim3(256), dim3(256), 0, stream, W1, W2, Ws, w1dt, w2t, wcst);
    hipLaunchKernelGGL(edgeconv_main, dim3(GRID), dim3(512), 0, stream,
                       feat, knn, w1dt, w2t, wcst, b1, b2, bs, gamma, beta, out);
}

// Round 6
// 205.763 us; speedup vs baseline: 2.1882x; 2.1882x over previous
//
#include <hip/hip_runtime.h>
#include <hip/hip_bf16.h>
#include <math.h>

#define NPTS 30000
#define KNN  16
#define NB   30          // batches (of 4 points) per block
#define GRID 250         // 250 * 120 pts = 30000 exactly

typedef __attribute__((ext_vector_type(8)))  __bf16 bf16x8;
typedef __attribute__((ext_vector_type(16))) float  f32x16;
typedef __attribute__((ext_vector_type(4)))  float  f32x4;

__device__ __forceinline__ unsigned short f2bf(float x) {
    unsigned u = __builtin_bit_cast(unsigned, x);
    return (unsigned short)((u + 0x7FFFu + ((u >> 16) & 1u)) >> 16);   // RNE
}
__device__ __forceinline__ float bf_lo(unsigned u) { return __builtin_bit_cast(float, u << 16); }
__device__ __forceinline__ float bf_hi(unsigned u) { return __builtin_bit_cast(float, u & 0xffff0000u); }
__device__ __forceinline__ unsigned pk2(float a, float b) {
    return (unsigned)f2bf(a) | ((unsigned)f2bf(b) << 16);
}
// tanh-form GELU: x*(1 - 1/(exp(1.5958*(x+0.044715x^3)) + 1))
__device__ __forceinline__ float gelu_t(float x) {
    float x2 = x * x;
    float u  = x * fmaf(0.07135481624f, x2, 1.59576912161f);
    float e  = __expf(u);
    float r  = __builtin_amdgcn_rcpf(e + 1.0f);
    return fmaf(-x, r, x);
}

// ---- prep: bf16 weight layouts in ws ----
// w1dt[d][k] = W1[128+k][d]          (256x128)  A-frags for GEMM1 (diff half)
// w2t [e][c] = W2[c][e]              (256x256)  B-frags for GEMM2
// wcst[col][k] = col<256 ? W1[k][col] : Ws[k][col-256]   (512x128) B for c2-pass
__global__ void prep_w(const float* __restrict__ W1, const float* __restrict__ W2,
                       const float* __restrict__ Ws,
                       unsigned short* __restrict__ w1dt, unsigned short* __restrict__ w2t,
                       unsigned short* __restrict__ wcst) {
    int t = blockIdx.x * 256 + threadIdx.x;          // grid 256*256 -> t < 65536
    {   int e = t >> 8, c = t & 255;
        w2t[t] = f2bf(W2[c * 256 + e]); }
    {   int col = t >> 7, k = t & 127;
        float v = (col < 256) ? W1[k * 256 + col] : Ws[k * 256 + (col - 256)];
        wcst[t] = f2bf(v); }
    if (t < 32768) {
        int d = t >> 7, k = t & 127;
        w1dt[t] = f2bf(W1[(128 + k) * 256 + d]); }
}

// UNIFORM waves: every wave owns 32 output channels for BOTH GEMMs.
// Persistent regs/wave: 8 W1d frags (32 VGPR) + 16 W2 frags (64 VGPR) = 96.
// Per iter i: {stage(i+1); c2pass every 4th (wv>=4)} B1 {LN(i-1) wv<4; GEMM1(i)->s_h} B2 {GEMM2(i)->max->s_agg}
__global__ __launch_bounds__(512, 1) void edgeconv_main(
    const float* __restrict__ feat, const int* __restrict__ knn,
    const unsigned short* __restrict__ w1dt, const unsigned short* __restrict__ w2t,
    const unsigned short* __restrict__ wcst,
    const float* __restrict__ b1, const float* __restrict__ b2,
    const float* __restrict__ bs,
    const float* __restrict__ gamma, const float* __restrict__ beta,
    float* __restrict__ out)
{
    __shared__ __align__(16) unsigned char  s_edge[2][64 * 256];   // 32 KB diff-edge bf16, swizzled
    __shared__ __align__(16) unsigned char  s_h[64 * 512];         // 32 KB h bf16, swizzled (single buf)
    __shared__ __align__(16) unsigned short s_c2[2][16][512];      // 32 KB [pt][cterm|skip]
    __shared__ __align__(16) float s_agg[2][4][256];               //  8 KB channel max

    const int lane = threadIdx.x & 63;
    const int wv   = threadIdx.x >> 6;      // 0..7
    const int l31  = lane & 31;
    const int lh   = lane >> 5;
    const int l15  = lane & 15;
    const int l4   = lane >> 4;
    const int pblock = blockIdx.x * 120;
    const int chb = wv * 32;                // this wave's 32 channels

    // persistent weight fragments: 96 VGPR total
    bf16x8 w1f[8], w2f[16];
    #pragma unroll
    for (int ks = 0; ks < 8; ++ks)
        w1f[ks] = *(const bf16x8*)(w1dt + (chb + l31) * 128 + ks * 16 + lh * 8);
    #pragma unroll
    for (int ks = 0; ks < 16; ++ks)
        w2f[ks] = *(const bf16x8*)(w2t + (chb + l31) * 256 + ks * 16 + lh * 8);

    // c2-pass on waves 4..7: 16 pts x 512 cols (cterm+b1 | skip+bs+b2)
    auto c2pass = [&](int s) {
        const int buf = s & 1;
        const int pb  = pblock + s * 16;
        bf16x8 af[4];
        #pragma unroll
        for (int ks = 0; ks < 4; ++ks) {
            int p = pb + l15; p = (p < NPTS) ? p : (NPTS - 1);
            const float* fp = feat + (long)p * 128 + ks * 32 + l4 * 8;
            float4 f0 = *(const float4*)fp;
            float4 f1 = *(const float4*)(fp + 4);
            uint4 u;
            u.x = pk2(f0.x, f0.y); u.y = pk2(f0.z, f0.w);
            u.z = pk2(f1.x, f1.y); u.w = pk2(f1.z, f1.w);
            af[ks] = __builtin_bit_cast(bf16x8, u);
        }
        #pragma unroll
        for (int j = 0; j < 8; ++j) {
            const int ct  = (wv - 4) * 8 + j;            // 0..31
            const int col = ct * 16 + l15;
            float bias = (ct < 16) ? b1[col] : (bs[col - 256] + b2[col - 256]);
            f32x4 acc = {bias, bias, bias, bias};
            #pragma unroll
            for (int ks = 0; ks < 4; ++ks) {
                bf16x8 bf = *(const bf16x8*)(wcst + col * 128 + ks * 32 + l4 * 8);
                acc = __builtin_amdgcn_mfma_f32_16x16x32_bf16(af[ks], bf, acc, 0, 0, 0);
            }
            #pragma unroll
            for (int r = 0; r < 4; ++r)
                s_c2[buf][l4 * 4 + r][col] = f2bf(acc[r]);
        }
    };

    // stage batch bt: each wave gathers 8 edge rows (half a point)
    auto stage = [&](int bt) {
        const int pt = wv >> 1;
        const int n  = pblock + bt * 4 + pt;
        const int kb = (wv & 1) * 8;
        float2 cc = *(const float2*)(feat + (long)n * 128 + lane * 2);
        int idx[8];
        #pragma unroll
        for (int kk = 0; kk < 8; ++kk) idx[kk] = knn[n * 16 + kb + kk];
        #pragma unroll
        for (int kk = 0; kk < 8; ++kk) {
            float2 nb = *(const float2*)(feat + (long)idx[kk] * 128 + lane * 2);
            int row = pt * 16 + kb + kk;
            unsigned v = pk2(nb.x - cc.x, nb.y - cc.y);
            *(unsigned*)(s_edge[bt & 1] + row * 256 + ((unsigned)(lane * 4) ^ (unsigned)((row & 7) << 4))) = v;
        }
    };

    // ---- prologue ----
    stage(0);
    if (wv >= 4) c2pass(0);

    const f32x16 z16 = (f32x16)0.0f;

    #pragma unroll 1
    for (int i = 0; i <= NB; ++i) {
        if (i + 1 < NB) stage(i + 1);
        if ((i & 3) == 2 && ((i >> 2) + 1) < 8 && wv >= 4)
            c2pass((i >> 2) + 1);
        __syncthreads();   // B1: edge(i+1)/c2 visible; agg(i-1) stable for LN

        // ---- LayerNorm(i-1) on waves 0-3 ----
        if (i >= 1 && wv < 4) {
            const int bt2 = i - 1;
            const int n   = pblock + bt2 * 4 + wv;
            const int sB  = (bt2 >> 2) & 1;
            const int pt16 = (bt2 & 3) * 4 + wv;
            float4 ag = *(const float4*)&s_agg[bt2 & 1][wv][lane * 4];
            uint2 sk  = *(const uint2*)(&s_c2[sB][pt16][256 + lane * 4]);
            float x0 = ag.x + bf_lo(sk.x), x1 = ag.y + bf_hi(sk.x);
            float x2 = ag.z + bf_lo(sk.y), x3 = ag.w + bf_hi(sk.y);
            float s  = x0 + x1 + x2 + x3;
            float ss = fmaf(x0, x0, fmaf(x1, x1, fmaf(x2, x2, x3 * x3)));
            #pragma unroll
            for (int off = 1; off < 64; off <<= 1) {
                s  += __shfl_xor(s, off);
                ss += __shfl_xor(ss, off);
            }
            float mu   = s * (1.0f / 256.0f);
            float var  = ss * (1.0f / 256.0f) - mu * mu;
            float rstd = rsqrtf(var + 1e-5f);
            float4 g4 = *(const float4*)&gamma[lane * 4];
            float4 b4 = *(const float4*)&beta[lane * 4];
            float4 o;
            o.x = (x0 - mu) * rstd * g4.x + b4.x;
            o.y = (x1 - mu) * rstd * g4.y + b4.y;
            o.z = (x2 - mu) * rstd * g4.z + b4.z;
            o.w = (x3 - mu) * rstd * g4.w + b4.w;
            *(float4*)&out[(long)n * 256 + lane * 4] = o;
        }

        // ---- GEMM1(i): h[row][ch] = gelu(edge_diff . W1d + cterm) ----
        if (i < NB) {
            const int sB = (i >> 2) & 1;
            f32x16 acc1[2] = {z16, z16};
            #pragma unroll
            for (int rowb = 0; rowb < 2; ++rowb) {
                const int row = rowb * 32 + l31;
                const unsigned swz = (unsigned)((row & 7) << 4);
                const unsigned rb = (unsigned)row * 256u;
                #pragma unroll
                for (int ks = 0; ks < 8; ++ks) {
                    bf16x8 bf = *(const bf16x8*)(s_edge[i & 1] + rb + ((unsigned)(ks * 32 + lh * 16) ^ swz));
                    acc1[rowb] = __builtin_amdgcn_mfma_f32_32x32x16_bf16(w1f[ks], bf, acc1[rowb], 0, 0, 0);
                }
            }
            #pragma unroll
            for (int rowb = 0; rowb < 2; ++rowb) {
                const int row  = rowb * 32 + l31;
                const int pt16 = (i & 3) * 4 + rowb * 2 + (l31 >> 4);
                const unsigned swz = (unsigned)((row & 7) << 4);
                #pragma unroll
                for (int g = 0; g < 4; ++g) {
                    const int ch0 = chb + 8 * g + 4 * lh;
                    uint2 c2v = *(const uint2*)(&s_c2[sB][pt16][ch0]);
                    float v0 = gelu_t(acc1[rowb][4 * g + 0] + bf_lo(c2v.x));
                    float v1 = gelu_t(acc1[rowb][4 * g + 1] + bf_hi(c2v.x));
                    float v2 = gelu_t(acc1[rowb][4 * g + 2] + bf_lo(c2v.y));
                    float v3 = gelu_t(acc1[rowb][4 * g + 3] + bf_hi(c2v.y));
                    uint2 hv; hv.x = pk2(v0, v1); hv.y = pk2(v2, v3);
                    *(uint2*)(s_h + (unsigned)row * 512u + ((unsigned)(ch0 * 2) ^ swz)) = hv;
                }
            }
        }
        __syncthreads();   // B2: h visible

        // ---- GEMM2(i): eo[row][ch] = h . W2; in-lane max over rows -> s_agg ----
        if (i < NB) {
            #pragma unroll
            for (int rowb = 0; rowb < 2; ++rowb) {
                const int row = rowb * 32 + l31;
                const unsigned swz = (unsigned)((row & 7) << 4);
                const unsigned rb = (unsigned)row * 512u;
                f32x16 a2 = z16;
                #pragma unroll
                for (int ks = 0; ks < 16; ++ks) {
                    bf16x8 hf = *(const bf16x8*)(s_h + rb + ((unsigned)(ks * 32 + lh * 16) ^ swz));
                    a2 = __builtin_amdgcn_mfma_f32_32x32x16_bf16(hf, w2f[ks], a2, 0, 0, 0);
                }
                float m0 = a2[0], m1 = a2[8];
                #pragma unroll
                for (int r = 1; r < 8; ++r) {
                    m0 = fmaxf(m0, a2[r]);
                    m1 = fmaxf(m1, a2[8 + r]);
                }
                m0 = fmaxf(m0, __shfl_xor(m0, 32));
                m1 = fmaxf(m1, __shfl_xor(m1, 32));
                if (lh == 0) {
                    s_agg[i & 1][rowb * 2 + 0][chb + l31] = m0;
                    s_agg[i & 1][rowb * 2 + 1][chb + l31] = m1;
                }
            }
        }
    }
}

extern "C" void kernel_launch(void* const* d_in, const int* in_sizes, int n_in,
                              void* d_out, int out_size, void* d_ws, size_t ws_size,
                              hipStream_t stream) {
    const float* feat  = (const float*)d_in[0];
    const int*   knn   = (const int*)  d_in[1];
    const float* W1    = (const float*)d_in[2];
    const float* b1    = (const float*)d_in[3];
    const float* W2    = (const float*)d_in[4];
    const float* b2    = (const float*)d_in[5];
    const float* Ws    = (const float*)d_in[6];
    const float* bs    = (const float*)d_in[7];
    const float* gamma = (const float*)d_in[8];
    const float* beta  = (const float*)d_in[9];
    float* out = (float*)d_out;

    unsigned short* w1dt = (unsigned short*)d_ws;          //  64 KB
    unsigned short* w2t  = w1dt + 32768;                   // 128 KB
    unsigned short* wcst = w2t + 65536;                    // 128 KB  (total 320 KB)

    hipLaunchKernelGGL(prep_w, dim3(256), dim3(256), 0, stream, W1, W2, Ws, w1dt, w2t, wcst);
    hipLaunchKernelGGL(edgeconv_main, dim3(GRID), dim3(512), 0, stream,
                       feat, knn, w1dt, w2t, wcst, b1, b2, bs, gamma, beta, out);
}

// Round 7
// 201.920 us; speedup vs baseline: 2.2298x; 1.0190x over previous
//
#include <hip/hip_runtime.h>
#include <hip/hip_bf16.h>
#include <math.h>

#define NPTS 30000
#define KNN  16
#define NB   30          // batches (of 4 points) per block
#define GRID 250         // 250 * 120 pts = 30000 exactly

typedef __attribute__((ext_vector_type(8)))  __bf16 bf16x8;
typedef __attribute__((ext_vector_type(16))) float  f32x16;
typedef __attribute__((ext_vector_type(4)))  float  f32x4;

__device__ __forceinline__ unsigned short f2bf(float x) {
    __bf16 b = (__bf16)x;                       // native cvt (RNE), compiler packs pairs
    return __builtin_bit_cast(unsigned short, b);
}
__device__ __forceinline__ unsigned pk2(float a, float b) {
    return (unsigned)f2bf(a) | ((unsigned)f2bf(b) << 16);
}
__device__ __forceinline__ float bf_lo(unsigned u) { return __builtin_bit_cast(float, u << 16); }
__device__ __forceinline__ float bf_hi(unsigned u) { return __builtin_bit_cast(float, u & 0xffff0000u); }
// tanh-form GELU: x*(1 - 1/(exp(1.5958*(x+0.044715x^3)) + 1))
__device__ __forceinline__ float gelu_t(float x) {
    float x2 = x * x;
    float u  = x * fmaf(0.07135481624f, x2, 1.59576912161f);
    float e  = __expf(u);
    float r  = __builtin_amdgcn_rcpf(e + 1.0f);
    return fmaf(-x, r, x);
}

// ---- prep: bf16 weight layouts in ws ----
// w1dt[d][k] = W1[128+k][d]          (256x128)  A-frags for GEMM1 (diff half)
// w2t [e][c] = W2[c][e]              (256x256)  B-frags for GEMM2
// wcst[col][k] = col<256 ? W1[k][col] : Ws[k][col-256]   (512x128) B for c2-pass
__global__ void prep_w(const float* __restrict__ W1, const float* __restrict__ W2,
                       const float* __restrict__ Ws,
                       unsigned short* __restrict__ w1dt, unsigned short* __restrict__ w2t,
                       unsigned short* __restrict__ wcst) {
    int t = blockIdx.x * 256 + threadIdx.x;          // grid 256*256 -> t < 65536
    {   int e = t >> 8, c = t & 255;
        w2t[t] = f2bf(W2[c * 256 + e]); }
    {   int col = t >> 7, k = t & 127;
        float v = (col < 256) ? W1[k * 256 + col] : Ws[k * 256 + (col - 256)];
        wcst[t] = f2bf(v); }
    if (t < 32768) {
        int d = t >> 7, k = t & 127;
        w1dt[t] = f2bf(W1[(128 + k) * 256 + d]); }
}

// Uniform waves, ONE barrier per iteration (software pipeline inside the wave):
//   iter i: issue gathers(i+1) | GEMM2(i-1) | GEMM1(i) | LN(i-2) | c2pass(every 4th)
//           | pack+write edges(i+1)  -> barrier
// Buffer parity: edge[i&1] read by G1(i), written for i+1; h[i&1] written by G1(i),
// read by G2(i) next iter; agg[(i-1)&1] written by G2(i-1), read by LN two iters later;
// c2 buf s&1 written at i=4s-2, first read i=4s, last read i=4s+5.
__global__ __launch_bounds__(512, 1) void edgeconv_main(
    const float* __restrict__ feat, const int* __restrict__ knn,
    const unsigned short* __restrict__ w1dt, const unsigned short* __restrict__ w2t,
    const unsigned short* __restrict__ wcst,
    const float* __restrict__ b1, const float* __restrict__ b2,
    const float* __restrict__ bs,
    const float* __restrict__ gamma, const float* __restrict__ beta,
    float* __restrict__ out)
{
    __shared__ __align__(16) unsigned char  s_edge[2][64 * 256];   // 32 KB diff-edge bf16, swz (row&15)<<4
    __shared__ __align__(16) unsigned char  s_h[2][64 * 512];      // 64 KB h bf16, swz (row&31)<<4
    __shared__ __align__(16) unsigned short s_c2[2][16][512];      // 32 KB [pt][cterm|skip]
    __shared__ __align__(16) float s_agg[2][4][256];               //  8 KB channel max
    // 136 KB total -> 1 block/CU

    const int lane = threadIdx.x & 63;
    const int wv   = threadIdx.x >> 6;      // 0..7
    const int l31  = lane & 31;
    const int lh   = lane >> 5;
    const int l15  = lane & 15;
    const int l4   = lane >> 4;
    const int pblock = blockIdx.x * 120;
    const int chb = wv * 32;                // this wave's 32 channels (both GEMMs)

    // persistent weight fragments: 96 VGPR
    bf16x8 w1f[8], w2f[16];
    #pragma unroll
    for (int ks = 0; ks < 8; ++ks)
        w1f[ks] = *(const bf16x8*)(w1dt + (chb + l31) * 128 + ks * 16 + lh * 8);
    #pragma unroll
    for (int ks = 0; ks < 16; ++ks)
        w2f[ks] = *(const bf16x8*)(w2t + (chb + l31) * 256 + ks * 16 + lh * 8);

    // c2-pass: 16 pts x 512 cols (cterm+b1 | skip+bs+b2), all 8 waves, 4 tiles each
    auto c2pass = [&](int s) {
        const int buf = s & 1;
        const int pb  = pblock + s * 16;
        bf16x8 af[4];
        #pragma unroll
        for (int ks = 0; ks < 4; ++ks) {
            int p = pb + l15; p = (p < NPTS) ? p : (NPTS - 1);
            const float* fp = feat + (long)p * 128 + ks * 32 + l4 * 8;
            float4 f0 = *(const float4*)fp;
            float4 f1 = *(const float4*)(fp + 4);
            uint4 u;
            u.x = pk2(f0.x, f0.y); u.y = pk2(f0.z, f0.w);
            u.z = pk2(f1.x, f1.y); u.w = pk2(f1.z, f1.w);
            af[ks] = __builtin_bit_cast(bf16x8, u);
        }
        #pragma unroll
        for (int j = 0; j < 4; ++j) {
            const int ct  = wv * 4 + j;                  // 0..31
            const int col = ct * 16 + l15;
            float bias = (ct < 16) ? b1[col] : (bs[col - 256] + b2[col - 256]);
            f32x4 acc = {bias, bias, bias, bias};
            #pragma unroll
            for (int ks = 0; ks < 4; ++ks) {
                bf16x8 bf = *(const bf16x8*)(wcst + col * 128 + ks * 32 + l4 * 8);
                acc = __builtin_amdgcn_mfma_f32_16x16x32_bf16(af[ks], bf, acc, 0, 0, 0);
            }
            #pragma unroll
            for (int r = 0; r < 4; ++r)
                s_c2[buf][l4 * 4 + r][col] = f2bf(acc[r]);
        }
    };

    // each wave stages 8 edge rows: point wv>>1, neighbors (wv&1)*8 ..+8
    const int st_pt = wv >> 1;
    const int st_kb = (wv & 1) * 8;

    // ---- prologue: stage batch 0, c2 super-batch 0 ----
    {
        const int n = pblock + st_pt;
        float2 cc = *(const float2*)(feat + (long)n * 128 + lane * 2);
        #pragma unroll
        for (int kk = 0; kk < 8; ++kk) {
            int idx = knn[n * 16 + st_kb + kk];
            float2 nb = *(const float2*)(feat + (long)idx * 128 + lane * 2);
            int row = st_pt * 16 + st_kb + kk;
            unsigned v = pk2(nb.x - cc.x, nb.y - cc.y);
            *(unsigned*)(s_edge[0] + row * 256 + ((unsigned)(lane * 4) ^ (unsigned)((row & 15) << 4))) = v;
        }
    }
    c2pass(0);
    __syncthreads();

    const f32x16 z16 = (f32x16)0.0f;

    #pragma unroll 1
    for (int i = 0; i <= NB + 1; ++i) {
        // ---- A) issue gather loads for batch i+1 (consumed at F, ~full iter later) ----
        float2 cc; float2 nbr[8];
        const bool doStage = (i + 1 < NB);
        if (doStage) {
            const int n = pblock + (i + 1) * 4 + st_pt;
            cc = *(const float2*)(feat + (long)n * 128 + lane * 2);
            int idx[8];
            #pragma unroll
            for (int kk = 0; kk < 8; ++kk) idx[kk] = knn[n * 16 + st_kb + kk];
            #pragma unroll
            for (int kk = 0; kk < 8; ++kk)
                nbr[kk] = *(const float2*)(feat + (long)idx[kk] * 128 + lane * 2);
        }

        // ---- B) GEMM2(i-1): eo = h . W2; in-lane max over rows -> s_agg ----
        if (i >= 1 && i <= NB) {
            const int bt = i - 1;
            #pragma unroll
            for (int rowb = 0; rowb < 2; ++rowb) {
                const int row = rowb * 32 + l31;
                const unsigned swz = (unsigned)((row & 31) << 4);
                const unsigned rb = (unsigned)row * 512u;
                f32x16 a2 = z16;
                #pragma unroll
                for (int ks = 0; ks < 16; ++ks) {
                    bf16x8 hf = *(const bf16x8*)(s_h[bt & 1] + rb + ((unsigned)(ks * 32 + lh * 16) ^ swz));
                    a2 = __builtin_amdgcn_mfma_f32_32x32x16_bf16(hf, w2f[ks], a2, 0, 0, 0);
                }
                float m0 = a2[0], m1 = a2[8];
                #pragma unroll
                for (int r = 1; r < 8; ++r) {
                    m0 = fmaxf(m0, a2[r]);
                    m1 = fmaxf(m1, a2[8 + r]);
                }
                m0 = fmaxf(m0, __shfl_xor(m0, 32));
                m1 = fmaxf(m1, __shfl_xor(m1, 32));
                if (lh == 0) {
                    s_agg[bt & 1][rowb * 2 + 0][chb + l31] = m0;
                    s_agg[bt & 1][rowb * 2 + 1][chb + l31] = m1;
                }
            }
        }

        // ---- C) GEMM1(i): h = gelu(edge_diff . W1d + cterm) -> s_h[i&1] ----
        if (i < NB) {
            const int sB = (i >> 2) & 1;
            f32x16 acc1[2] = {z16, z16};
            #pragma unroll
            for (int rowb = 0; rowb < 2; ++rowb) {
                const int row = rowb * 32 + l31;
                const unsigned swz = (unsigned)((row & 15) << 4);
                const unsigned rb = (unsigned)row * 256u;
                #pragma unroll
                for (int ks = 0; ks < 8; ++ks) {
                    bf16x8 bf = *(const bf16x8*)(s_edge[i & 1] + rb + ((unsigned)(ks * 32 + lh * 16) ^ swz));
                    acc1[rowb] = __builtin_amdgcn_mfma_f32_32x32x16_bf16(w1f[ks], bf, acc1[rowb], 0, 0, 0);
                }
            }
            #pragma unroll
            for (int rowb = 0; rowb < 2; ++rowb) {
                const int row  = rowb * 32 + l31;
                const int pt16 = (i & 3) * 4 + rowb * 2 + (l31 >> 4);
                const unsigned swz = (unsigned)((row & 31) << 4);
                #pragma unroll
                for (int g = 0; g < 4; ++g) {
                    const int ch0 = chb + 8 * g + 4 * lh;
                    uint2 c2v = *(const uint2*)(&s_c2[sB][pt16][ch0]);   // broadcast read
                    float v0 = gelu_t(acc1[rowb][4 * g + 0] + bf_lo(c2v.x));
                    float v1 = gelu_t(acc1[rowb][4 * g + 1] + bf_hi(c2v.x));
                    float v2 = gelu_t(acc1[rowb][4 * g + 2] + bf_lo(c2v.y));
                    float v3 = gelu_t(acc1[rowb][4 * g + 3] + bf_hi(c2v.y));
                    uint2 hv; hv.x = pk2(v0, v1); hv.y = pk2(v2, v3);
                    *(uint2*)(s_h[i & 1] + (unsigned)row * 512u + ((unsigned)(ch0 * 2) ^ swz)) = hv;
                }
            }
        }

        // ---- D) LayerNorm(i-2) on waves 0-3 ----
        if (i >= 2 && wv < 4) {
            const int bt2 = i - 2;
            const int n   = pblock + bt2 * 4 + wv;
            const int sB  = (bt2 >> 2) & 1;
            const int pt16 = (bt2 & 3) * 4 + wv;
            float4 ag = *(const float4*)&s_agg[bt2 & 1][wv][lane * 4];
            uint2 sk  = *(const uint2*)(&s_c2[sB][pt16][256 + lane * 4]);
            float x0 = ag.x + bf_lo(sk.x), x1 = ag.y + bf_hi(sk.x);
            float x2 = ag.z + bf_lo(sk.y), x3 = ag.w + bf_hi(sk.y);
            float s  = x0 + x1 + x2 + x3;
            float ss = fmaf(x0, x0, fmaf(x1, x1, fmaf(x2, x2, x3 * x3)));
            #pragma unroll
            for (int off = 1; off < 64; off <<= 1) {
                s  += __shfl_xor(s, off);
                ss += __shfl_xor(ss, off);
            }
            float mu   = s * (1.0f / 256.0f);
            float var  = ss * (1.0f / 256.0f) - mu * mu;
            float rstd = rsqrtf(var + 1e-5f);
            float4 g4 = *(const float4*)&gamma[lane * 4];
            float4 b4 = *(const float4*)&beta[lane * 4];
            float4 o;
            o.x = (x0 - mu) * rstd * g4.x + b4.x;
            o.y = (x1 - mu) * rstd * g4.y + b4.y;
            o.z = (x2 - mu) * rstd * g4.z + b4.z;
            o.w = (x3 - mu) * rstd * g4.w + b4.w;
            *(float4*)&out[(long)n * 256 + lane * 4] = o;
        }

        // ---- E) c2 super-batch s at i=4s-2 (first read i=4s, prev buf free after i=4s-3) ----
        if ((i & 3) == 2) {
            int s = (i + 2) >> 2;
            if (s < 8) c2pass(s);
        }

        // ---- F) pack + LDS-write staged edges (loads from A complete here) ----
        if (doStage) {
            const int bt = i + 1;
            #pragma unroll
            for (int kk = 0; kk < 8; ++kk) {
                int row = st_pt * 16 + st_kb + kk;
                unsigned v = pk2(nbr[kk].x - cc.x, nbr[kk].y - cc.y);
                *(unsigned*)(s_edge[bt & 1] + row * 256 + ((unsigned)(lane * 4) ^ (unsigned)((row & 15) << 4))) = v;
            }
        }
        __syncthreads();
    }
}

extern "C" void kernel_launch(void* const* d_in, const int* in_sizes, int n_in,
                              void* d_out, int out_size, void* d_ws, size_t ws_size,
                              hipStream_t stream) {
    const float* feat  = (const float*)d_in[0];
    const int*   knn   = (const int*)  d_in[1];
    const float* W1    = (const float*)d_in[2];
    const float* b1    = (const float*)d_in[3];
    const float* W2    = (const float*)d_in[4];
    const float* b2    = (const float*)d_in[5];
    const float* Ws    = (const float*)d_in[6];
    const float* bs    = (const float*)d_in[7];
    const float* gamma = (const float*)d_in[8];
    const float* beta  = (const float*)d_in[9];
    float* out = (float*)d_out;

    unsigned short* w1dt = (unsigned short*)d_ws;          //  64 KB
    unsigned short* w2t  = w1dt + 32768;                   // 128 KB
    unsigned short* wcst = w2t + 65536;                    // 128 KB  (total 320 KB)

    hipLaunchKernelGGL(prep_w, dim3(256), dim3(256), 0, stream, W1, W2, Ws, w1dt, w2t, wcst);
    hipLaunchKernelGGL(edgeconv_main, dim3(GRID), dim3(512), 0, stream,
                       feat, knn, w1dt, w2t, wcst, b1, b2, bs, gamma, beta, out);
}